// Round 5
// baseline (25.468 us; speedup 1.0000x reference)
//
#include <hip/hip_runtime.h>

// out[b][i][j][k] = ah[b][i] * vh[b][j] * th[b][k], ah/vh/th = [1, row].
// B=128, D=63 -> padded 64. Flat layout: (((b*64)+i)*64+j)*64+k.
// Store-BW-bound: 134 MB fp32 out, ~96 KB in. 512 blocks x 1024 threads:
// each block writes a 256 KB contiguous region (16 i-slabs). Per thread,
// j=tid>>4 and k=(tid&15)*4 are loop-invariant -> 2 LDS reads cover all
// 16 stores; the store loop is pure VALU+store, walking the region
// sequentially. Plain cached stores (nt regressed: 25.9->29.4 us, R3).

__global__ __launch_bounds__(1024) void tensorFusion_kernel(
    const float* __restrict__ t,
    const float* __restrict__ a,
    const float* __restrict__ v,
    float* __restrict__ out)
{
    const int D   = 63;
    const int blk = blockIdx.x;        // 0..511
    const int b   = blk >> 2;          // batch
    const int i0  = (blk & 3) << 4;    // first of 16 consecutive i values

    __shared__ float vh[64];
    __shared__ float th[64];
    __shared__ float ah[64];

    const int tid = threadIdx.x;       // 0..1023
    if (tid < 64) {
        vh[tid] = (tid == 0) ? 1.0f : v[b * D + tid - 1];
        th[tid] = (tid == 0) ? 1.0f : t[b * D + tid - 1];
        ah[tid] = (tid == 0) ? 1.0f : a[b * D + tid - 1];
    }
    __syncthreads();

    // Loop-invariant per-thread operands.
    const float  vj = vh[tid >> 4];                                  // j = tid>>4
    const float4 tk = reinterpret_cast<const float4*>(th)[tid & 15]; // k = (tid&15)*4

    // 16 a-values for this block's i-slabs, via 4 vector LDS reads
    // (uniform address per wave -> broadcast, conflict-free).
    const float4* ah4 = reinterpret_cast<const float4*>(ah);
    const float4 av0 = ah4[(i0 >> 2) + 0];
    const float4 av1 = ah4[(i0 >> 2) + 1];
    const float4 av2 = ah4[(i0 >> 2) + 2];
    const float4 av3 = ah4[(i0 >> 2) + 3];
    const float a_vals[16] = {av0.x, av0.y, av0.z, av0.w,
                              av1.x, av1.y, av1.z, av1.w,
                              av2.x, av2.y, av2.z, av2.w,
                              av3.x, av3.y, av3.z, av3.w};

    // Block's contiguous region: 16 slabs * 1024 float4 = 256 KB.
    float4* __restrict__ outp =
        reinterpret_cast<float4*>(out) + ((size_t)b * 64 + i0) * 1024;

    #pragma unroll
    for (int n = 0; n < 16; ++n) {     // slab index (i = i0 + n)
        const float s = a_vals[n] * vj;
        outp[n * 1024 + tid] = make_float4(s * tk.x, s * tk.y, s * tk.z, s * tk.w);
    }
}

extern "C" void kernel_launch(void* const* d_in, const int* in_sizes, int n_in,
                              void* d_out, int out_size, void* d_ws, size_t ws_size,
                              hipStream_t stream) {
    const float* t = (const float*)d_in[0];
    const float* a = (const float*)d_in[1];
    const float* v = (const float*)d_in[2];
    float* out = (float*)d_out;

    // 128 batches * 4 i-groups = 512 blocks (2/CU, 32 waves/CU, tail-free).
    tensorFusion_kernel<<<dim3(128 * 4), dim3(1024), 0, stream>>>(t, a, v, out);
}